// Round 3
// baseline (1216.426 us; speedup 1.0000x reference)
//
#include <hip/hip_runtime.h>
#include <math.h>

// Router: x (4,8192,1024) f32, W (64,1024) f32
// out = [ top_idx (32768,2) as float | top_gates (32768,2) | loss (1) ]
// ws  = 64 floats of per-expert prob sums (atomic accumulated)
//
// R3: W read via VECTOR global_load_dwordx4 (divergent-typed pointer, all
// lanes same addr -> 1 txn, L1-hot). R1/R2 used the scalar path (s_load),
// which shares lgkmcnt with ds_read and returns out-of-order -> full
// lgkmcnt(0) drains every c-step -> 16% VALUBusy ceiling.

constexpr int DMODEL = 1024;
constexpr int NEXP   = 64;
constexpr int BM     = 64;    // tokens per workgroup
constexpr int BK     = 64;    // K per staging tile
constexpr int NWAVE  = 8;
constexpr int EPW    = NEXP / NWAVE;   // 8 experts per wave
constexpr int NTOK   = 32768;
constexpr int NTILE  = DMODEL / BK;    // 16

__global__ __launch_bounds__(512, 4) void router_kernel(
    const float* __restrict__ x, const float* __restrict__ W,
    float* __restrict__ out, float* __restrict__ expert_sums)
{
    // x tile, XOR-swizzled: (token t, k-chunk c) lives at xs[c][t ^ (c&7)]
    __shared__ __align__(16) float xs[BK / 4][BM][4];
    __shared__ float lmax[NWAVE][BM];
    __shared__ float lsum[NWAVE][BM];
    __shared__ float ltv[NWAVE][BM][2];
    __shared__ int   lti[NWAVE][BM][2];

    const int tid  = threadIdx.x;
    const int lane = tid & 63;
    const int w    = tid >> 6;
    const int tok0 = blockIdx.x * BM;

    // DIVERGENT-typed W base (no readfirstlane!) -> compiler emits vector
    // global_load_dwordx4; runtime-uniform addr coalesces to one txn.
    const float* Wb = W + (size_t)(tid >> 6) * (EPW * DMODEL);

    float4 acc[EPW];
#pragma unroll
    for (int e = 0; e < EPW; ++e) acc[e] = make_float4(0.f, 0.f, 0.f, 0.f);

    // staging map: each thread owns 2 float4 chunks per tile
    const int st_t0 = tid >> 4;          // rows for it=0 (0..31), +32 for it=1
    const int st_c  = tid & 15;
    const float* gsrc0 = x + (size_t)(tok0 + st_t0) * DMODEL + st_c * 4;
    const float* gsrc1 = x + (size_t)(tok0 + st_t0 + 32) * DMODEL + st_c * 4;

    // prefetch tile 0
    float4 r0 = *reinterpret_cast<const float4*>(gsrc0);
    float4 r1 = *reinterpret_cast<const float4*>(gsrc1);

    for (int tile = 0; tile < NTILE; ++tile) {
        const int k0 = tile * BK;
        __syncthreads();   // xs free to overwrite
        *reinterpret_cast<float4*>(&xs[st_c][st_t0 ^ (st_c & 7)][0]) = r0;
        *reinterpret_cast<float4*>(&xs[st_c][(st_t0 + 32) ^ (st_c & 7)][0]) = r1;
        if (tile + 1 < NTILE) {   // issue next tile's loads, consumed later
            r0 = *reinterpret_cast<const float4*>(gsrc0 + (tile + 1) * BK);
            r1 = *reinterpret_cast<const float4*>(gsrc1 + (tile + 1) * BK);
        }
        __syncthreads();   // xs ready

#pragma unroll
        for (int c = 0; c < BK / 4; ++c) {
            float4 xv = *reinterpret_cast<const float4*>(&xs[c][lane ^ (c & 7)][0]);
            float4 wc[EPW];
#pragma unroll
            for (int e = 0; e < EPW; ++e) {
                wc[e] = *reinterpret_cast<const float4*>(
                    Wb + (size_t)e * DMODEL + k0 + c * 4);
            }
#pragma unroll
            for (int e = 0; e < EPW; ++e) {
                acc[e].x = fmaf(xv.x, wc[e].x, acc[e].x);
                acc[e].y = fmaf(xv.y, wc[e].y, acc[e].y);
                acc[e].z = fmaf(xv.z, wc[e].z, acc[e].z);
                acc[e].w = fmaf(xv.w, wc[e].w, acc[e].w);
            }
        }
    }

    // ---- epilogue ----
    float logit[EPW];
    float lm = -INFINITY;
#pragma unroll
    for (int e = 0; e < EPW; ++e) {
        logit[e] = (acc[e].x + acc[e].y) + (acc[e].z + acc[e].w);
        lm = fmaxf(lm, logit[e]);
    }
    lmax[w][lane] = lm;
    __syncthreads();
    float gmax = -INFINITY;
#pragma unroll
    for (int ww = 0; ww < NWAVE; ++ww) gmax = fmaxf(gmax, lmax[ww][lane]);

    // local top-2, total order: value desc, index asc (matches lax.top_k)
    float v0 = -INFINITY, v1 = -INFINITY;
    int   i0 = NEXP, i1 = NEXP;
#pragma unroll
    for (int e = 0; e < EPW; ++e) {
        float v = logit[e];
        int  gi = w * EPW + e;
        if (v > v0) { v1 = v0; i1 = i0; v0 = v; i0 = gi; }
        else if (v > v1) { v1 = v; i1 = gi; }
    }

    float p[EPW];
    float s = 0.f;
#pragma unroll
    for (int e = 0; e < EPW; ++e) { p[e] = __expf(logit[e] - gmax); s += p[e]; }

    lsum[w][lane] = s;
    ltv[w][lane][0] = v0; ltv[w][lane][1] = v1;
    lti[w][lane][0] = i0; lti[w][lane][1] = i1;
    __syncthreads();

    float gsum = 0.f;
#pragma unroll
    for (int ww = 0; ww < NWAVE; ++ww) gsum += lsum[ww][lane];
    const float inv = 1.0f / gsum;

    // per-expert prob sums over this WG's 64 tokens -> one atomic per (wave, expert)
#pragma unroll
    for (int e = 0; e < EPW; ++e) {
        float v = p[e] * inv;
#pragma unroll
        for (int off = 32; off; off >>= 1) v += __shfl_xor(v, off, 64);
        if (lane == 0) atomicAdd(&expert_sums[w * EPW + e], v);
    }

    // wave 0 merges the 8 waves' top-2 candidates and writes idx + gates
    if (tid < 64) {
        const int l = tid;
        float bv0 = -INFINITY, bv1 = -INFINITY;
        int   bi0 = NEXP, bi1 = NEXP;
#pragma unroll
        for (int ww = 0; ww < NWAVE; ++ww) {
#pragma unroll
            for (int j = 0; j < 2; ++j) {
                float v  = ltv[ww][l][j];
                int   gi = lti[ww][l][j];
                bool b0 = (v > bv0) || (v == bv0 && gi < bi0);
                if (b0) { bv1 = bv0; bi1 = bi0; bv0 = v; bi0 = gi; }
                else {
                    bool b1 = (v > bv1) || (v == bv1 && gi < bi1);
                    if (b1) { bv1 = v; bi1 = gi; }
                }
            }
        }
        float g     = __expf(bv1 - bv0);
        float denom = 1.0f + g;
        float g0 = 1.0f / denom;
        float g1 = g / denom;

        size_t tok = (size_t)tok0 + l;
        reinterpret_cast<float2*>(out)[tok]            = make_float2((float)bi0, (float)bi1);
        reinterpret_cast<float2*>(out + 2 * NTOK)[tok] = make_float2(g0, g1);
    }
}

__global__ void loss_kernel(const float* __restrict__ sums, float* __restrict__ out)
{
    const int lane = threadIdx.x;  // 64 threads
    float pv = sums[lane] * (1.0f / (float)NTOK);  // avg_probs[lane]
    float m = pv;
#pragma unroll
    for (int off = 32; off; off >>= 1) m += __shfl_xor(m, off, 64);
    m *= (1.0f / (float)NEXP);
    float d = pv - m;
    float v = d * d;
#pragma unroll
    for (int off = 32; off; off >>= 1) v += __shfl_xor(v, off, 64);
    v *= (1.0f / (float)(NEXP - 1));  // ddof=1
    if (lane == 0) {
        float stdv = sqrtf(v);
        float r = stdv / (m + 1e-6f);
        out[4 * NTOK] = r * r;
    }
}

extern "C" void kernel_launch(void* const* d_in, const int* in_sizes, int n_in,
                              void* d_out, int out_size, void* d_ws, size_t ws_size,
                              hipStream_t stream)
{
    const float* x = (const float*)d_in[0];
    const float* W = (const float*)d_in[1];
    float* out  = (float*)d_out;
    float* sums = (float*)d_ws;

    hipMemsetAsync(d_ws, 0, NEXP * sizeof(float), stream);

    hipLaunchKernelGGL(router_kernel, dim3(NTOK / BM), dim3(512), 0, stream,
                       x, W, out, sums);
    hipLaunchKernelGGL(loss_kernel, dim3(1), dim3(64), 0, stream, sums, out);
}

// Round 4
// 264.126 us; speedup vs baseline: 4.6055x; 4.6055x over previous
//
#include <hip/hip_runtime.h>
#include <math.h>

// Router: x (4,8192,1024) f32, W (64,1024) f32
// out = [ top_idx (32768,2) as float | top_gates (32768,2) | loss (1) ]
// ws  = 64 floats of per-expert prob sums (atomic accumulated)
//
// R4 design:
//  - block = 512 thr (8 waves) covers 128 tokens x ALL 64 experts; grid = 256 (1 block/CU)
//  - wave w owns experts [8w, 8w+8): W per k-step is wave-uniform -> uniform
//    global_load_dwordx4 (1 txn, L1-hot, vmcnt pipe — never mixes with DS lgkmcnt)
//  - thread-tile: 2 tokens (lane, lane+64) x 8 experts, float4-split accumulators
//    (same summation tree as the R1/R2 kernels that passed)
//  - x staged to LDS via global_load_lds width=16, XOR-chunk swizzle applied on the
//    GLOBAL source (linear LDS dest), double-buffered, 1 barrier/tile
//  - launch_bounds(512,2): VGPR cap 256 — avoids R3's spill catastrophe

constexpr int DMODEL = 1024;
constexpr int NEXP   = 64;
constexpr int BM     = 128;   // tokens per block
constexpr int BK     = 64;    // K per tile
constexpr int NWAVE  = 8;
constexpr int NTOK   = 32768;
constexpr int NTILE  = DMODEL / BK;  // 16

__device__ __forceinline__ void gload16(const float* g, float* l) {
    __builtin_amdgcn_global_load_lds(
        (const __attribute__((address_space(1))) unsigned int*)g,
        (__attribute__((address_space(3))) unsigned int*)l,
        16, 0, 0);
}

__global__ __launch_bounds__(512, 2) void router_kernel(
    const float* __restrict__ x, const float* __restrict__ W,
    float* __restrict__ out, float* __restrict__ expert_sums)
{
    // xs[buf][row][64 floats]; row r stores logical 16B-chunk c at phys chunk c ^ (r&15)
    __shared__ __align__(16) float xs[2][BM][BK];
    __shared__ float lmax[NWAVE][BM];
    __shared__ float lsum[NWAVE][BM];
    __shared__ float ltv[NWAVE][BM][2];
    __shared__ int   lti[NWAVE][BM][2];

    const int tid  = threadIdx.x;
    const int lane = tid & 63;
    const int w    = tid >> 6;           // wave id 0..7
    const int tok0 = blockIdx.x * BM;

    // divergent-typed W base (vector loads, vmcnt); wave-uniform value
    const float* Wb = W + (size_t)(tid >> 6) * (8 * DMODEL);

    float4 acc0[8], acc1[8];
#pragma unroll
    for (int e = 0; e < 8; ++e) {
        acc0[e] = make_float4(0.f, 0.f, 0.f, 0.f);
        acc1[e] = make_float4(0.f, 0.f, 0.f, 0.f);
    }

    // ---- staging: wave w stages rows [w*16, w*16+16) via 4 instrs x 4 rows ----
    // lane L of instr i: row r = w*16+i*4 + (L>>4), phys chunk c = L&15,
    // src chunk = c ^ (r&15)  (so LDS phys chunk c holds logical chunk c^(r&15))
    auto stage = [&](int buf, int tile) {
#pragma unroll
        for (int i = 0; i < 4; ++i) {
            const int r0 = w * 16 + i * 4;
            const int r  = r0 + (lane >> 4);
            const int c  = lane & 15;
            const float* src = x + (size_t)(tok0 + r) * DMODEL + tile * BK
                                 + ((c ^ (r & 15)) << 2);
            float* dst = &xs[buf][r0][0] + (lane << 2);
            gload16(src, dst);
        }
    };

    stage(0, 0);
    __syncthreads();

    int cur = 0;
    for (int tile = 0; tile < NTILE; ++tile) {
        if (tile + 1 < NTILE) stage(cur ^ 1, tile + 1);
        const int k0 = tile * BK;
        const int sw_base = lane & 15;
#pragma unroll 4
        for (int kg = 0; kg < BK / 4; ++kg) {
            const int sw = (kg ^ sw_base) << 2;
            const float4 xv0 = *reinterpret_cast<const float4*>(&xs[cur][lane][sw]);
            const float4 xv1 = *reinterpret_cast<const float4*>(&xs[cur][lane + 64][sw]);
#pragma unroll
            for (int e = 0; e < 8; ++e) {
                const float4 wv = *reinterpret_cast<const float4*>(
                    Wb + e * DMODEL + k0 + (kg << 2));
                acc0[e].x = fmaf(xv0.x, wv.x, acc0[e].x);
                acc0[e].y = fmaf(xv0.y, wv.y, acc0[e].y);
                acc0[e].z = fmaf(xv0.z, wv.z, acc0[e].z);
                acc0[e].w = fmaf(xv0.w, wv.w, acc0[e].w);
                acc1[e].x = fmaf(xv1.x, wv.x, acc1[e].x);
                acc1[e].y = fmaf(xv1.y, wv.y, acc1[e].y);
                acc1[e].z = fmaf(xv1.z, wv.z, acc1[e].z);
                acc1[e].w = fmaf(xv1.w, wv.w, acc1[e].w);
            }
        }
        __syncthreads();   // stage(t+1) complete (vmcnt drain) + buf reuse guard
        cur ^= 1;
    }

    // ---- epilogue: tokens t0 = tok0+lane, t1 = tok0+lane+64 ----
    float l0[8], l1[8];
    float m0 = -INFINITY, m1 = -INFINITY;
#pragma unroll
    for (int e = 0; e < 8; ++e) {
        l0[e] = (acc0[e].x + acc0[e].y) + (acc0[e].z + acc0[e].w);
        l1[e] = (acc1[e].x + acc1[e].y) + (acc1[e].z + acc1[e].w);
        m0 = fmaxf(m0, l0[e]);
        m1 = fmaxf(m1, l1[e]);
    }
    lmax[w][lane] = m0;
    lmax[w][lane + 64] = m1;
    __syncthreads();

    float g0 = -INFINITY, g1 = -INFINITY;
#pragma unroll
    for (int ww = 0; ww < NWAVE; ++ww) {
        g0 = fmaxf(g0, lmax[ww][lane]);
        g1 = fmaxf(g1, lmax[ww][lane + 64]);
    }

    float p0[8], p1[8];
    float s0 = 0.f, s1 = 0.f;
#pragma unroll
    for (int e = 0; e < 8; ++e) {
        p0[e] = __expf(l0[e] - g0); s0 += p0[e];
        p1[e] = __expf(l1[e] - g1); s1 += p1[e];
    }
    lsum[w][lane] = s0;
    lsum[w][lane + 64] = s1;

    // local top-2 per token over this wave's 8 experts (value desc, index asc)
    {
        float v0 = -INFINITY, v1 = -INFINITY; int i0 = NEXP, i1 = NEXP;
        float u0 = -INFINITY, u1 = -INFINITY; int j0 = NEXP, j1 = NEXP;
#pragma unroll
        for (int e = 0; e < 8; ++e) {
            const int gi = w * 8 + e;
            float v = l0[e];
            if (v > v0) { v1 = v0; i1 = i0; v0 = v; i0 = gi; }
            else if (v > v1) { v1 = v; i1 = gi; }
            float u = l1[e];
            if (u > u0) { u1 = u0; j1 = j0; u0 = u; j0 = gi; }
            else if (u > u1) { u1 = u; j1 = gi; }
        }
        ltv[w][lane][0] = v0; ltv[w][lane][1] = v1;
        lti[w][lane][0] = i0; lti[w][lane][1] = i1;
        ltv[w][lane + 64][0] = u0; ltv[w][lane + 64][1] = u1;
        lti[w][lane + 64][0] = j0; lti[w][lane + 64][1] = j1;
    }
    __syncthreads();

    float gs0 = 0.f, gs1 = 0.f;
#pragma unroll
    for (int ww = 0; ww < NWAVE; ++ww) {
        gs0 += lsum[ww][lane];
        gs1 += lsum[ww][lane + 64];
    }
    const float inv0 = 1.0f / gs0;
    const float inv1 = 1.0f / gs1;

    // per-expert prob sums over this block's 128 tokens -> 1 atomic per (wave, e)
#pragma unroll
    for (int e = 0; e < 8; ++e) {
        float v = p0[e] * inv0 + p1[e] * inv1;
#pragma unroll
        for (int off = 32; off; off >>= 1) v += __shfl_xor(v, off, 64);
        if (lane == 0) atomicAdd(&expert_sums[w * 8 + e], v);
    }

    // waves 0-1 merge the 8 waves' candidates and write idx + gates
    if (tid < BM) {
        const int t = tid;
        float bv0 = -INFINITY, bv1 = -INFINITY;
        int   bi0 = NEXP, bi1 = NEXP;
#pragma unroll
        for (int ww = 0; ww < NWAVE; ++ww) {
#pragma unroll
            for (int j = 0; j < 2; ++j) {
                float v  = ltv[ww][t][j];
                int   gi = lti[ww][t][j];
                bool b0 = (v > bv0) || (v == bv0 && gi < bi0);
                if (b0) { bv1 = bv0; bi1 = bi0; bv0 = v; bi0 = gi; }
                else {
                    bool b1 = (v > bv1) || (v == bv1 && gi < bi1);
                    if (b1) { bv1 = v; bi1 = gi; }
                }
            }
        }
        float g     = __expf(bv1 - bv0);
        float denom = 1.0f + g;
        float ga = 1.0f / denom;
        float gb = g / denom;

        size_t tok = (size_t)tok0 + t;
        reinterpret_cast<float2*>(out)[tok]            = make_float2((float)bi0, (float)bi1);
        reinterpret_cast<float2*>(out + 2 * NTOK)[tok] = make_float2(ga, gb);
    }
}

__global__ void loss_kernel(const float* __restrict__ sums, float* __restrict__ out)
{
    const int lane = threadIdx.x;  // 64 threads
    float pv = sums[lane] * (1.0f / (float)NTOK);  // avg_probs[lane]
    float m = pv;
#pragma unroll
    for (int off = 32; off; off >>= 1) m += __shfl_xor(m, off, 64);
    m *= (1.0f / (float)NEXP);
    float d = pv - m;
    float v = d * d;
#pragma unroll
    for (int off = 32; off; off >>= 1) v += __shfl_xor(v, off, 64);
    v *= (1.0f / (float)(NEXP - 1));  // ddof=1
    if (lane == 0) {
        float stdv = sqrtf(v);
        float r = stdv / (m + 1e-6f);
        out[4 * NTOK] = r * r;
    }
}

extern "C" void kernel_launch(void* const* d_in, const int* in_sizes, int n_in,
                              void* d_out, int out_size, void* d_ws, size_t ws_size,
                              hipStream_t stream)
{
    const float* x = (const float*)d_in[0];
    const float* W = (const float*)d_in[1];
    float* out  = (float*)d_out;
    float* sums = (float*)d_ws;

    hipMemsetAsync(d_ws, 0, NEXP * sizeof(float), stream);

    hipLaunchKernelGGL(router_kernel, dim3(NTOK / BM), dim3(512), 0, stream,
                       x, W, out, sums);
    hipLaunchKernelGGL(loss_kernel, dim3(1), dim3(64), 0, stream, sums, out);
}